// Round 1
// baseline (1491.191 us; speedup 1.0000x reference)
//
#include <hip/hip_runtime.h>
#include <math.h>

typedef __bf16 bf16;
typedef bf16 bf16x8 __attribute__((ext_vector_type(8)));
typedef float f32x4 __attribute__((ext_vector_type(4)));

#define LDS_PAD 40  // 32 k-elems padded to 40 -> 80B row stride, 2-way-max bank aliasing

// ---------------- transpose fp32 (R,C) -> bf16 (C,R) ----------------
__global__ __launch_bounds__(256) void k_transpose(const float* __restrict__ src, bf16* __restrict__ dst,
                                                   int R, int C, long srcZ, long dstZ)
{
    __shared__ float tile[32][33];
    int tx = threadIdx.x & 31, ty = threadIdx.x >> 5;
    long sz = (long)blockIdx.z * srcZ, dz = (long)blockIdx.z * dstZ;
    int c0 = blockIdx.x * 32, r0 = blockIdx.y * 32;
#pragma unroll
    for (int j = 0; j < 4; ++j)
        tile[ty + 8 * j][tx] = src[sz + (long)(r0 + ty + 8 * j) * C + c0 + tx];
    __syncthreads();
#pragma unroll
    for (int j = 0; j < 4; ++j)
        dst[dz + (long)(c0 + ty + 8 * j) * R + r0 + tx] = (bf16)tile[tx][ty + 8 * j];
}

// ---------------- CSR of adjacency (incl. self loops), <=64 nnz/row ----------------
__global__ __launch_bounds__(256) void k_csr(const float* __restrict__ adj, int* __restrict__ cnt,
                                             unsigned short* __restrict__ cols)
{
    int row = blockIdx.x * 4 + (threadIdx.x >> 6);
    int lane = threadIdx.x & 63;
    int base = 0;
    for (int c0 = 0; c0 < 2048; c0 += 64) {
        float a = adj[(long)row * 2048 + c0 + lane];
        unsigned long long m = __ballot(a != 0.0f);
        if (a != 0.0f) {
            int pos = base + __popcll(m & ((1ull << lane) - 1ull));
            if (pos < 64) cols[(long)row * 64 + pos] = (unsigned short)(c0 + lane);
        }
        base += __popcll(m);
    }
    if (lane == 0) cnt[row] = base < 64 ? base : 64;
}

// ---------------- single-block sparse power iteration -> lam_max ----------------
// L*v via CSR of adjacency(+I): cnt = deg+1; (L v)_i = cnt_i*v_i - sum_{cols} v_j
__global__ __launch_bounds__(1024) void k_power(const int* __restrict__ cnt, const unsigned short* __restrict__ cols,
                                                float* __restrict__ lamOut)
{
    __shared__ float va[2048], vb[2048];
    __shared__ float redf[16];
    __shared__ int   redi[16];
    __shared__ float bcast;
    int t = threadIdx.x;
    int wid = t >> 6, lane = t & 63;

    // Gershgorin scale: lamG = 2*maxdeg >= lam_max
    int md = 0;
    for (int i = t; i < 2048; i += 1024) md = max(md, cnt[i]);
#pragma unroll
    for (int off = 32; off >= 1; off >>= 1) md = max(md, __shfl_xor(md, off));
    if (lane == 0) redi[wid] = md;
    __syncthreads();
    if (t == 0) {
        int m = 0;
        for (int i = 0; i < 16; ++i) m = max(m, redi[i]);
        bcast = (float)(2 * (m - 1));
    }
    __syncthreads();
    float lamG = bcast;
    float invG = lamG > 0.0f ? 1.0f / lamG : 0.0f;

    // pseudo-random +/- init (NOT constant: ones is the 0-eigenvector)
    for (int i = t; i < 2048; i += 1024) {
        unsigned u = (unsigned)i * 2654435761u;
        u ^= u >> 16; u *= 2246822519u; u ^= u >> 13;
        float mag = 0.5f + (float)((u >> 9) & 1023) * (1.0f / 1024.0f);
        va[i] = (u & 1) ? mag : -mag;
    }
    __syncthreads();

    float* cur = va; float* nxt = vb;
    for (int it = 0; it < 64; ++it) {
        for (int i = t; i < 2048; i += 1024) {
            int c = cnt[i];
            const unsigned short* cl = cols + (long)i * 64;
            float sum = 0.0f;
            for (int j = 0; j < c; ++j) sum += cur[cl[j]];
            nxt[i] = ((float)c * cur[i] - sum) * invG;
        }
        __syncthreads();
        float* tmp = cur; cur = nxt; nxt = tmp;
        if ((it & 15) == 15) {  // renorm to dodge under/overflow
            float p = 0.0f;
            for (int i = t; i < 2048; i += 1024) p += cur[i] * cur[i];
#pragma unroll
            for (int off = 32; off >= 1; off >>= 1) p += __shfl_xor(p, off);
            if (lane == 0) redf[wid] = p;
            __syncthreads();
            if (t == 0) {
                float s = 0; for (int i = 0; i < 16; ++i) s += redf[i];
                bcast = s;
            }
            __syncthreads();
            float sc = rsqrtf(fmaxf(bcast, 1e-30f));
            for (int i = t; i < 2048; i += 1024) cur[i] *= sc;
            __syncthreads();
        }
    }
    // exact fp32 Rayleigh quotient
    float num = 0.0f, den = 0.0f;
    for (int i = t; i < 2048; i += 1024) {
        int c = cnt[i];
        const unsigned short* cl = cols + (long)i * 64;
        float sum = 0.0f;
        for (int j = 0; j < c; ++j) sum += cur[cl[j]];
        float y = (float)c * cur[i] - sum;
        num += y * cur[i];
        den += cur[i] * cur[i];
    }
#pragma unroll
    for (int off = 32; off >= 1; off >>= 1) { num += __shfl_xor(num, off); den += __shfl_xor(den, off); }
    if (lane == 0) { redf[wid] = num; redi[wid] = __float_as_int(den); }
    __syncthreads();
    if (t == 0) {
        float n = 0, d = 0;
        for (int i = 0; i < 16; ++i) { n += redf[i]; d += __int_as_float(redi[i]); }
        lamOut[0] = (d > 0.0f ? n / d : 0.0f) + 1e-8f;
    }
}

// ---------------- bf16 MFMA GEMM, BM=64 BN=256 BK=32, fused epilogues ----------------
// out[m][n] = sum_k A[m][k] * BT[n][k]   (BT is pre-transposed, k-contiguous, bf16)
// EPI: 0 = store bf16 | 1 = +bias,LN,relu,+resid -> f32+bf16 | 2 = +bias,+resid,LN -> f32(+bf16) | 3 = +bias,gelu -> bf16
template <int TA_BF16, int TRANS_A, int EPI>
__global__ __launch_bounds__(256) void k_gemm(
    const void* __restrict__ Av, const bf16* __restrict__ BTg,
    float* __restrict__ outF, bf16* __restrict__ outB,
    const float* __restrict__ bias, const float* __restrict__ resid,
    const float* __restrict__ gam, const float* __restrict__ bet,
    const float* __restrict__ lamPtr,
    int K, int ldA, long aZ, long btZ, long outZrows, int ldOut)
{
    __shared__ bf16 As[64 * LDS_PAD];
    __shared__ bf16 Bs[256 * LDS_PAD];

    int tid = threadIdx.x;
    int w = tid >> 6, lane = tid & 63;
    int q = lane >> 4, l15 = lane & 15;
    int rowBlk = blockIdx.x * 64;
    int colB = blockIdx.y * 256;
    const bf16* BT = BTg + (long)blockIdx.z * btZ + (long)blockIdx.y * 256 * (long)K;

    float s2 = 0.0f;
    if (TRANS_A) s2 = 2.0f / lamPtr[0];  // L_norm = s2*L - I applied during staging

    f32x4 acc[16];
#pragma unroll
    for (int i = 0; i < 16; ++i) acc[i] = (f32x4){0.0f, 0.0f, 0.0f, 0.0f};

    int ar = tid >> 2, ac = (tid & 3) * 8;
    for (int kt = 0; kt < K; kt += 32) {
        {   // stage A tile 64x32 -> bf16 LDS
            long gr = rowBlk + ar;
            if (TA_BF16) {
                const bf16* A = (const bf16*)Av + (long)blockIdx.z * aZ;
                uint4 u = *(const uint4*)(A + gr * (long)ldA + kt + ac);
                *(uint4*)&As[ar * LDS_PAD + ac] = u;
            } else {
                const float* A = (const float*)Av + (long)blockIdx.z * aZ;
                const float* p = A + gr * (long)ldA + kt + ac;
                float4 f0 = *(const float4*)p;
                float4 f1 = *(const float4*)(p + 4);
                float f[8] = {f0.x, f0.y, f0.z, f0.w, f1.x, f1.y, f1.z, f1.w};
                if (TRANS_A) {
#pragma unroll
                    for (int j = 0; j < 8; ++j) {
                        float v = s2 * f[j];
                        if ((int)gr == kt + ac + j) v -= 1.0f;
                        f[j] = v;
                    }
                }
                union { bf16 h[8]; uint4 u; } pk;
#pragma unroll
                for (int j = 0; j < 8; ++j) pk.h[j] = (bf16)f[j];
                *(uint4*)&As[ar * LDS_PAD + ac] = pk.u;
            }
        }
        {   // stage BT tile 256x32 (already bf16, k-contiguous)
            const bf16* p = BT + (long)tid * K + kt;
            uint4 u0 = ((const uint4*)p)[0];
            uint4 u1 = ((const uint4*)p)[1];
            uint4 u2 = ((const uint4*)p)[2];
            uint4 u3 = ((const uint4*)p)[3];
            bf16* d = &Bs[tid * LDS_PAD];
            *(uint4*)(d + 0)  = u0;
            *(uint4*)(d + 8)  = u1;
            *(uint4*)(d + 16) = u2;
            *(uint4*)(d + 24) = u3;
        }
        __syncthreads();
        bf16x8 a = *(const bf16x8*)&As[(w * 16 + l15) * LDS_PAD + q * 8];
#pragma unroll
        for (int nt = 0; nt < 16; ++nt) {
            bf16x8 b = *(const bf16x8*)&Bs[(nt * 16 + l15) * LDS_PAD + q * 8];
            acc[nt] = __builtin_amdgcn_mfma_f32_16x16x32_bf16(a, b, acc[nt], 0, 0, 0);
        }
        __syncthreads();
    }

    // ---- epilogue: lane holds rows (q*4+r), col l15, per 16-col tile nt ----
    long zRow = (long)blockIdx.z * outZrows + rowBlk + w * 16 + q * 4;  // + r

    if (EPI == 0) {
#pragma unroll
        for (int nt = 0; nt < 16; ++nt) {
            int col = colB + nt * 16 + l15;
#pragma unroll
            for (int r = 0; r < 4; ++r)
                outB[(zRow + r) * (long)ldOut + col] = (bf16)acc[nt][r];
        }
        return;
    }
    if (EPI == 3) {
#pragma unroll
        for (int nt = 0; nt < 16; ++nt) {
            int col = colB + nt * 16 + l15;
            float bi = bias[col];
#pragma unroll
            for (int r = 0; r < 4; ++r) {
                float v = acc[nt][r] + bi;
                float g = 0.5f * v * (1.0f + erff(v * 0.70710678118654752440f));  // exact gelu
                outB[(zRow + r) * (long)ldOut + col] = (bf16)g;
            }
        }
        return;
    }
    // EPI 1/2: layernorm over the full 256-wide row (in-register, 16-lane shuffles)
    float s[4] = {0, 0, 0, 0}, sq[4] = {0, 0, 0, 0};
#pragma unroll
    for (int nt = 0; nt < 16; ++nt) {
        int col = colB + nt * 16 + l15;
        float bi = bias[col];
#pragma unroll
        for (int r = 0; r < 4; ++r) {
            float v = acc[nt][r] + bi;
            if (EPI == 2) v += resid[(zRow + r) * 256 + col];  // residual BEFORE LN
            acc[nt][r] = v;
            s[r] += v; sq[r] += v * v;
        }
    }
#pragma unroll
    for (int off = 1; off <= 8; off <<= 1) {
#pragma unroll
        for (int r = 0; r < 4; ++r) { s[r] += __shfl_xor(s[r], off); sq[r] += __shfl_xor(sq[r], off); }
    }
    float mean[4], rstd[4];
#pragma unroll
    for (int r = 0; r < 4; ++r) {
        mean[r] = s[r] * (1.0f / 256.0f);
        float var = sq[r] * (1.0f / 256.0f) - mean[r] * mean[r];
        rstd[r] = rsqrtf(var + 1e-5f);
    }
#pragma unroll
    for (int nt = 0; nt < 16; ++nt) {
        int col = colB + nt * 16 + l15;
        float gc = gam[col], bc2 = bet[col];
#pragma unroll
        for (int r = 0; r < 4; ++r) {
            float v = (acc[nt][r] - mean[r]) * rstd[r] * gc + bc2;
            if (EPI == 1) v = fmaxf(v, 0.0f) + resid[(zRow + r) * 256 + col];  // relu then residual AFTER LN
            long oi = (zRow + r) * (long)ldOut + col;
            outF[oi] = v;
            if (outB) outB[oi] = (bf16)v;
        }
    }
}

// ---------------- sparse gather attention: block=(b,row), wave=head, lane=dim ----------------
__global__ __launch_bounds__(256) void k_attn(const bf16* __restrict__ qg, const bf16* __restrict__ kg,
                                              const bf16* __restrict__ vg, bf16* __restrict__ og,
                                              const int* __restrict__ cnt, const unsigned short* __restrict__ cols)
{
    __shared__ unsigned short sc[64];
    __shared__ float sp[4][64];
    int row = blockIdx.x;
    int b = row >> 11, i = row & 2047;
    int tid = threadIdx.x, h = tid >> 6, lane = tid & 63;
    int c = cnt[i];
    if (tid < 64) sc[tid] = cols[(long)i * 64 + tid];
    __syncthreads();
    long qoff = (long)row * 256 + h * 64 + lane;
    float qd = (float)qg[qoff];
    long kvBase = (long)b * 2048;
    for (int j = 0; j < c; ++j) {
        int col = sc[j];
        float kd = (float)kg[(kvBase + col) * 256 + h * 64 + lane];
        float p = qd * kd;
#pragma unroll
        for (int off = 32; off >= 1; off >>= 1) p += __shfl_xor(p, off);
        if (lane == 0) sp[h][j] = p * 0.125f;  // 1/sqrt(64)
    }
    __syncthreads();
    float sj = (lane < c) ? sp[h][lane] : -3.0e38f;
    float mx = sj;
#pragma unroll
    for (int off = 32; off >= 1; off >>= 1) mx = fmaxf(mx, __shfl_xor(mx, off));
    float e = (lane < c) ? __expf(sj - mx) : 0.0f;
    float ssum = e;
#pragma unroll
    for (int off = 32; off >= 1; off >>= 1) ssum += __shfl_xor(ssum, off);
    if (lane < c) sp[h][lane] = e / ssum;
    __syncthreads();
    float acc = 0.0f;
    for (int j = 0; j < c; ++j) {
        int col = sc[j];
        acc += sp[h][j] * (float)vg[(kvBase + col) * 256 + h * 64 + lane];
    }
    og[qoff] = (bf16)acc;
}

// ---------------- launcher ----------------
extern "C" void kernel_launch(void* const* d_in, const int* in_sizes, int n_in,
                              void* d_out, int out_size, void* d_ws, size_t ws_size,
                              hipStream_t stream)
{
    const float* x   = (const float*)d_in[0];
    const float* L   = (const float*)d_in[1];
    const float* adj = (const float*)d_in[2];
    const float* Wc  = (const float*)d_in[3];
    const float* bc  = (const float*)d_in[4];
    const float* g1  = (const float*)d_in[5];
    const float* be1 = (const float*)d_in[6];
    const float* Wq  = (const float*)d_in[7];
    const float* Wk  = (const float*)d_in[8];
    const float* Wv  = (const float*)d_in[9];
    const float* Wo  = (const float*)d_in[10];
    const float* bo  = (const float*)d_in[11];
    const float* g2  = (const float*)d_in[12];
    const float* be2 = (const float*)d_in[13];
    const float* W1  = (const float*)d_in[14];
    const float* b1  = (const float*)d_in[15];
    const float* W2  = (const float*)d_in[16];
    const float* b2  = (const float*)d_in[17];
    const float* g3  = (const float*)d_in[18];
    const float* be3 = (const float*)d_in[19];
    float* out = (float*)d_out;

    char* ws = (char*)d_ws;
    size_t off = 0;
    auto alloc = [&](size_t bytes) -> void* {
        void* p = ws + off;
        off = (off + bytes + 255) & ~(size_t)255;
        return p;
    };
    float* lam           = (float*)alloc(256);
    int* cnt             = (int*)alloc(2048 * 4);
    unsigned short* cols = (unsigned short*)alloc(2048 * 64 * 2);
    bf16* WcT = (bf16*)alloc(65536 * 2);
    bf16* WqT = (bf16*)alloc(65536 * 2);   // WqT,WkT,WvT contiguous (btZ = 65536)
    bf16* WkT = (bf16*)alloc(65536 * 2);
    bf16* WvT = (bf16*)alloc(65536 * 2);
    bf16* WoT = (bf16*)alloc(65536 * 2);
    bf16* W1T = (bf16*)alloc(131072 * 2);
    bf16* W2T = (bf16*)alloc(131072 * 2);
    bf16* xT  = (bf16*)alloc((size_t)4 * 256 * 2048 * 2);
    bf16* xp  = (bf16*)alloc((size_t)8192 * 256 * 2);
    float* x1f = (float*)alloc((size_t)8192 * 256 * 4);
    bf16* x1b  = (bf16*)alloc((size_t)8192 * 256 * 2);
    bf16* qb   = (bf16*)alloc((size_t)3 * 8192 * 256 * 2);
    bf16* ob   = (bf16*)alloc((size_t)8192 * 256 * 2);
    float* x2f = (float*)alloc((size_t)8192 * 256 * 4);
    bf16* x2b  = (bf16*)alloc((size_t)8192 * 256 * 2);
    bf16* m1   = (bf16*)alloc((size_t)8192 * 512 * 2);
    (void)in_sizes; (void)n_in; (void)out_size; (void)ws_size;

    dim3 blk(256);
    // sparse structure + lam_max
    k_csr<<<dim3(512), blk, 0, stream>>>(adj, cnt, cols);
    k_power<<<dim3(1), dim3(1024), 0, stream>>>(cnt, cols, lam);
    // pre-transpose B operands to bf16 k-contiguous
    k_transpose<<<dim3(8, 8, 1), blk, 0, stream>>>(Wc, WcT, 256, 256, 0, 0);
    k_transpose<<<dim3(8, 8, 1), blk, 0, stream>>>(Wq, WqT, 256, 256, 0, 0);
    k_transpose<<<dim3(8, 8, 1), blk, 0, stream>>>(Wk, WkT, 256, 256, 0, 0);
    k_transpose<<<dim3(8, 8, 1), blk, 0, stream>>>(Wv, WvT, 256, 256, 0, 0);
    k_transpose<<<dim3(8, 8, 1), blk, 0, stream>>>(Wo, WoT, 256, 256, 0, 0);
    k_transpose<<<dim3(16, 8, 1), blk, 0, stream>>>(W1, W1T, 256, 512, 0, 0);
    k_transpose<<<dim3(8, 16, 1), blk, 0, stream>>>(W2, W2T, 512, 256, 0, 0);
    k_transpose<<<dim3(8, 64, 4), blk, 0, stream>>>(x, xT, 2048, 256, 2048 * 256, 256 * 2048);

    // xp[b] = (2L/lam - I) @ x[b]    (A=L fp32 w/ on-the-fly transform, BT=xT per batch)
    k_gemm<0, 1, 0><<<dim3(32, 1, 4), blk, 0, stream>>>(
        (const void*)L, xT, nullptr, xp, nullptr, nullptr, nullptr, nullptr, lam,
        2048, 2048, 0L, (long)256 * 2048, 2048L, 256);
    // x1 = relu(LN(xp@Wc + bc; g1,be1)) + x
    k_gemm<1, 0, 1><<<dim3(128, 1, 1), blk, 0, stream>>>(
        (const void*)xp, WcT, x1f, x1b, bc, x, g1, be1, nullptr,
        256, 256, 0L, 0L, 0L, 256);
    // q,k,v = x1 @ {Wq,Wk,Wv}
    k_gemm<1, 0, 0><<<dim3(128, 1, 3), blk, 0, stream>>>(
        (const void*)x1b, WqT, nullptr, qb, nullptr, nullptr, nullptr, nullptr, nullptr,
        256, 256, 0L, 65536L, 8192L, 256);
    // sparse masked attention
    bf16* kb  = qb + (size_t)8192 * 256;
    bf16* vb2 = qb + (size_t)2 * 8192 * 256;
    k_attn<<<dim3(8192), blk, 0, stream>>>(qb, kb, vb2, ob, cnt, cols);
    // x2 = LN(x1 + o@Wo + bo; g2,be2)
    k_gemm<1, 0, 2><<<dim3(128, 1, 1), blk, 0, stream>>>(
        (const void*)ob, WoT, x2f, x2b, bo, x1f, g2, be2, nullptr,
        256, 256, 0L, 0L, 0L, 256);
    // m1 = gelu(x2@W1 + b1)
    k_gemm<1, 0, 3><<<dim3(128, 2, 1), blk, 0, stream>>>(
        (const void*)x2b, W1T, nullptr, m1, b1, nullptr, nullptr, nullptr, nullptr,
        256, 256, 0L, 0L, 0L, 512);
    // out = LN(x2 + m1@W2 + b2; g3,be3)
    k_gemm<1, 0, 2><<<dim3(128, 1, 1), blk, 0, stream>>>(
        (const void*)m1, W2T, out, nullptr, b2, x2f, g3, be3, nullptr,
        512, 512, 0L, 0L, 0L, 256);
}

// Round 2
// 579.055 us; speedup vs baseline: 2.5752x; 2.5752x over previous
//
#include <hip/hip_runtime.h>
#include <math.h>

typedef __bf16 bf16;
typedef bf16 bf16x8 __attribute__((ext_vector_type(8)));
typedef float f32x4 __attribute__((ext_vector_type(4)));

#define LDS_PAD 40  // 32 k-elems padded to 40 -> 80B row stride, 2-way-max bank aliasing
#define SENT 2048   // sentinel col index; v[SENT] == 0

// ---------------- merged transpose fp32 (R,C) -> bf16 (C,R), all matrices in one launch ----
__global__ __launch_bounds__(256) void k_trans_all(
    const float* __restrict__ Wc, const float* __restrict__ Wq, const float* __restrict__ Wk,
    const float* __restrict__ Wv, const float* __restrict__ Wo, const float* __restrict__ W1,
    const float* __restrict__ W2, const float* __restrict__ x,
    bf16* __restrict__ WcT, bf16* __restrict__ WqT, bf16* __restrict__ WkT,
    bf16* __restrict__ WvT, bf16* __restrict__ WoT, bf16* __restrict__ W1T,
    bf16* __restrict__ W2T, bf16* __restrict__ xT)
{
    __shared__ float tile[32][33];
    int z = blockIdx.z;
    const float* src; bf16* dst; int R, C;
    switch (z) {
        case 0: src = Wc; dst = WcT; R = 256; C = 256; break;
        case 1: src = Wq; dst = WqT; R = 256; C = 256; break;
        case 2: src = Wk; dst = WkT; R = 256; C = 256; break;
        case 3: src = Wv; dst = WvT; R = 256; C = 256; break;
        case 4: src = Wo; dst = WoT; R = 256; C = 256; break;
        case 5: src = W1; dst = W1T; R = 256; C = 512; break;
        case 6: src = W2; dst = W2T; R = 512; C = 256; break;
        default: {
            int b = z - 7;
            src = x + (long)b * 2048 * 256; dst = xT + (long)b * 256 * 2048;
            R = 2048; C = 256;
        }
    }
    int c0 = blockIdx.x * 32, r0 = blockIdx.y * 32;
    if (c0 >= C || r0 >= R) return;
    int tx = threadIdx.x & 31, ty = threadIdx.x >> 5;
#pragma unroll
    for (int j = 0; j < 4; ++j)
        tile[ty + 8 * j][tx] = src[(long)(r0 + ty + 8 * j) * C + c0 + tx];
    __syncthreads();
#pragma unroll
    for (int j = 0; j < 4; ++j)
        dst[(long)(c0 + ty + 8 * j) * R + r0 + tx] = (bf16)tile[tx][ty + 8 * j];
}

// ---------------- CSR of adjacency (incl. self loops), <=64 nnz/row, sentinel-padded ------
__global__ __launch_bounds__(256) void k_csr(const float* __restrict__ adj, int* __restrict__ cnt,
                                             unsigned short* __restrict__ cols)
{
    int row = blockIdx.x * 4 + (threadIdx.x >> 6);
    int lane = threadIdx.x & 63;
    int base = 0;
    for (int c0 = 0; c0 < 2048; c0 += 64) {
        float a = adj[(long)row * 2048 + c0 + lane];
        unsigned long long m = __ballot(a != 0.0f);
        if (a != 0.0f) {
            int pos = base + __popcll(m & ((1ull << lane) - 1ull));
            if (pos < 64) cols[(long)row * 64 + pos] = (unsigned short)(c0 + lane);
        }
        base += __popcll(m);
    }
    int c = base < 64 ? base : 64;
    if (lane >= c) cols[(long)row * 64 + lane] = (unsigned short)SENT;  // pad tail with sentinel
    if (lane == 0) cnt[row] = c;
}

// ---------------- single-block sparse power iteration -> lam_max ----------------
// (L v)_i = cnt_i*v_i - sum_{cols} v_j ; gathers via sentinel-padded ELL, unroll-8 ILP
__global__ __launch_bounds__(1024) void k_power(const int* __restrict__ cnt,
                                                const unsigned short* __restrict__ cols,
                                                float* __restrict__ lamOut)
{
    __shared__ float va[2064], vb[2064];   // [SENT] = 0
    __shared__ float redf[16], redf2[16];
    __shared__ int   redi[16];
    __shared__ float bcast;
    int t = threadIdx.x;
    int wid = t >> 6, lane = t & 63;
    int r0 = t, r1 = t + 1024;

    int c0 = cnt[r0], c1 = cnt[r1];
    int p0 = (c0 + 7) & ~7, p1 = (c1 + 7) & ~7;
    const unsigned short* cl0 = cols + (long)r0 * 64;
    const unsigned short* cl1 = cols + (long)r1 * 64;

    // Gershgorin scale: lamG = 2*maxdeg >= lam_max
    int md = max(c0, c1);
#pragma unroll
    for (int off = 32; off >= 1; off >>= 1) md = max(md, __shfl_xor(md, off));
    if (lane == 0) redi[wid] = md;
    __syncthreads();
    if (t == 0) {
        int m = 0;
        for (int i = 0; i < 16; ++i) m = max(m, redi[i]);
        bcast = (float)(2 * (m - 1));
    }
    // pseudo-random +/- init (NOT constant: ones is the 0-eigenvector)
    for (int i = t; i < 2048; i += 1024) {
        unsigned u = (unsigned)i * 2654435761u;
        u ^= u >> 16; u *= 2246822519u; u ^= u >> 13;
        float mag = 0.5f + (float)((u >> 9) & 1023) * (1.0f / 1024.0f);
        va[i] = (u & 1) ? mag : -mag;
    }
    if (t == 0) { va[SENT] = 0.0f; vb[SENT] = 0.0f; }
    __syncthreads();
    float lamG = bcast;
    float invG = lamG > 0.0f ? 1.0f / lamG : 0.0f;

    float* cur = va; float* nxt = vb;
    for (int it = 0; it < 64; ++it) {
        float d0 = cur[r0], d1 = cur[r1];
        float sum0 = 0.0f, sum1 = 0.0f;
        for (int j = 0; j < p0; j += 8) {          // 8 independent LDS gathers per uint4
            uint4 q = *(const uint4*)(cl0 + j);
            sum0 += cur[q.x & 0xffff] + cur[q.x >> 16] + cur[q.y & 0xffff] + cur[q.y >> 16]
                  + cur[q.z & 0xffff] + cur[q.z >> 16] + cur[q.w & 0xffff] + cur[q.w >> 16];
        }
        for (int j = 0; j < p1; j += 8) {
            uint4 q = *(const uint4*)(cl1 + j);
            sum1 += cur[q.x & 0xffff] + cur[q.x >> 16] + cur[q.y & 0xffff] + cur[q.y >> 16]
                  + cur[q.z & 0xffff] + cur[q.z >> 16] + cur[q.w & 0xffff] + cur[q.w >> 16];
        }
        nxt[r0] = ((float)c0 * d0 - sum0) * invG;
        nxt[r1] = ((float)c1 * d1 - sum1) * invG;
        __syncthreads();
        float* tmp = cur; cur = nxt; nxt = tmp;
        if ((it & 15) == 15) {  // renorm to dodge under/overflow
            float p = cur[r0] * cur[r0] + cur[r1] * cur[r1];
#pragma unroll
            for (int off = 32; off >= 1; off >>= 1) p += __shfl_xor(p, off);
            if (lane == 0) redf[wid] = p;
            __syncthreads();
            if (t == 0) {
                float s = 0; for (int i = 0; i < 16; ++i) s += redf[i];
                bcast = s;
            }
            __syncthreads();
            float sc = rsqrtf(fmaxf(bcast, 1e-30f));
            cur[r0] *= sc; cur[r1] *= sc;
            __syncthreads();
        }
    }
    // exact fp32 Rayleigh quotient (unscaled L)
    float d0 = cur[r0], d1 = cur[r1];
    float sum0 = 0.0f, sum1 = 0.0f;
    for (int j = 0; j < p0; j += 8) {
        uint4 q = *(const uint4*)(cl0 + j);
        sum0 += cur[q.x & 0xffff] + cur[q.x >> 16] + cur[q.y & 0xffff] + cur[q.y >> 16]
              + cur[q.z & 0xffff] + cur[q.z >> 16] + cur[q.w & 0xffff] + cur[q.w >> 16];
    }
    for (int j = 0; j < p1; j += 8) {
        uint4 q = *(const uint4*)(cl1 + j);
        sum1 += cur[q.x & 0xffff] + cur[q.x >> 16] + cur[q.y & 0xffff] + cur[q.y >> 16]
              + cur[q.z & 0xffff] + cur[q.z >> 16] + cur[q.w & 0xffff] + cur[q.w >> 16];
    }
    float num = ((float)c0 * d0 - sum0) * d0 + ((float)c1 * d1 - sum1) * d1;
    float den = d0 * d0 + d1 * d1;
#pragma unroll
    for (int off = 32; off >= 1; off >>= 1) { num += __shfl_xor(num, off); den += __shfl_xor(den, off); }
    if (lane == 0) { redf[wid] = num; redf2[wid] = den; }
    __syncthreads();
    if (t == 0) {
        float n = 0, d = 0;
        for (int i = 0; i < 16; ++i) { n += redf[i]; d += redf2[i]; }
        lamOut[0] = (d > 0.0f ? n / d : 0.0f) + 1e-8f;
    }
}

// ---------------- bf16 MFMA GEMM, BM=64 BN=256 BK=32, fused epilogues ----------------
// out[m][n] = sum_k A[m][k] * BT[n][k]   (BT is pre-transposed, k-contiguous, bf16)
// EPI: 0 = store bf16 | 1 = +bias,LN,relu,+resid -> f32+bf16 | 2 = +bias,+resid,LN -> f32(+bf16) | 3 = +bias,gelu -> bf16
template <int TA_BF16, int TRANS_A, int EPI>
__global__ __launch_bounds__(256) void k_gemm(
    const void* __restrict__ Av, const bf16* __restrict__ BTg,
    float* __restrict__ outF, bf16* __restrict__ outB,
    const float* __restrict__ bias, const float* __restrict__ resid,
    const float* __restrict__ gam, const float* __restrict__ bet,
    const float* __restrict__ lamPtr,
    int K, int ldA, long aZ, long btZ, long outZrows, int ldOut)
{
    __shared__ bf16 As[64 * LDS_PAD];
    __shared__ bf16 Bs[256 * LDS_PAD];

    int tid = threadIdx.x;
    int w = tid >> 6, lane = tid & 63;
    int q = lane >> 4, l15 = lane & 15;
    int rowBlk = blockIdx.x * 64;
    int colB = blockIdx.y * 256;
    const bf16* BT = BTg + (long)blockIdx.z * btZ + (long)blockIdx.y * 256 * (long)K;

    float s2 = 0.0f;
    if (TRANS_A) s2 = 2.0f / lamPtr[0];  // L_norm = s2*L - I applied during staging

    f32x4 acc[16];
#pragma unroll
    for (int i = 0; i < 16; ++i) acc[i] = (f32x4){0.0f, 0.0f, 0.0f, 0.0f};

    int ar = tid >> 2, ac = (tid & 3) * 8;
    for (int kt = 0; kt < K; kt += 32) {
        {   // stage A tile 64x32 -> bf16 LDS
            long gr = rowBlk + ar;
            if (TA_BF16) {
                const bf16* A = (const bf16*)Av + (long)blockIdx.z * aZ;
                uint4 u = *(const uint4*)(A + gr * (long)ldA + kt + ac);
                *(uint4*)&As[ar * LDS_PAD + ac] = u;
            } else {
                const float* A = (const float*)Av + (long)blockIdx.z * aZ;
                const float* p = A + gr * (long)ldA + kt + ac;
                float4 f0 = *(const float4*)p;
                float4 f1 = *(const float4*)(p + 4);
                float f[8] = {f0.x, f0.y, f0.z, f0.w, f1.x, f1.y, f1.z, f1.w};
                if (TRANS_A) {
#pragma unroll
                    for (int j = 0; j < 8; ++j) {
                        float v = s2 * f[j];
                        if ((int)gr == kt + ac + j) v -= 1.0f;
                        f[j] = v;
                    }
                }
                union { bf16 h[8]; uint4 u; } pk;
#pragma unroll
                for (int j = 0; j < 8; ++j) pk.h[j] = (bf16)f[j];
                *(uint4*)&As[ar * LDS_PAD + ac] = pk.u;
            }
        }
        {   // stage BT tile 256x32 (already bf16, k-contiguous)
            const bf16* p = BT + (long)tid * K + kt;
            uint4 u0 = ((const uint4*)p)[0];
            uint4 u1 = ((const uint4*)p)[1];
            uint4 u2 = ((const uint4*)p)[2];
            uint4 u3 = ((const uint4*)p)[3];
            bf16* d = &Bs[tid * LDS_PAD];
            *(uint4*)(d + 0)  = u0;
            *(uint4*)(d + 8)  = u1;
            *(uint4*)(d + 16) = u2;
            *(uint4*)(d + 24) = u3;
        }
        __syncthreads();
        bf16x8 a = *(const bf16x8*)&As[(w * 16 + l15) * LDS_PAD + q * 8];
#pragma unroll
        for (int nt = 0; nt < 16; ++nt) {
            bf16x8 b = *(const bf16x8*)&Bs[(nt * 16 + l15) * LDS_PAD + q * 8];
            acc[nt] = __builtin_amdgcn_mfma_f32_16x16x32_bf16(a, b, acc[nt], 0, 0, 0);
        }
        __syncthreads();
    }

    // ---- epilogue: lane holds rows (q*4+r), col l15, per 16-col tile nt ----
    long zRow = (long)blockIdx.z * outZrows + rowBlk + w * 16 + q * 4;  // + r

    if (EPI == 0) {
#pragma unroll
        for (int nt = 0; nt < 16; ++nt) {
            int col = colB + nt * 16 + l15;
#pragma unroll
            for (int r = 0; r < 4; ++r)
                outB[(zRow + r) * (long)ldOut + col] = (bf16)acc[nt][r];
        }
        return;
    }
    if (EPI == 3) {
#pragma unroll
        for (int nt = 0; nt < 16; ++nt) {
            int col = colB + nt * 16 + l15;
            float bi = bias[col];
#pragma unroll
            for (int r = 0; r < 4; ++r) {
                float v = acc[nt][r] + bi;
                float g = 0.5f * v * (1.0f + erff(v * 0.70710678118654752440f));  // exact gelu
                outB[(zRow + r) * (long)ldOut + col] = (bf16)g;
            }
        }
        return;
    }
    // EPI 1/2: layernorm over the full 256-wide row (in-register, 16-lane shuffles)
    float s[4] = {0, 0, 0, 0}, sq[4] = {0, 0, 0, 0};
#pragma unroll
    for (int nt = 0; nt < 16; ++nt) {
        int col = colB + nt * 16 + l15;
        float bi = bias[col];
#pragma unroll
        for (int r = 0; r < 4; ++r) {
            float v = acc[nt][r] + bi;
            if (EPI == 2) v += resid[(zRow + r) * 256 + col];  // residual BEFORE LN
            acc[nt][r] = v;
            s[r] += v; sq[r] += v * v;
        }
    }
#pragma unroll
    for (int off = 1; off <= 8; off <<= 1) {
#pragma unroll
        for (int r = 0; r < 4; ++r) { s[r] += __shfl_xor(s[r], off); sq[r] += __shfl_xor(sq[r], off); }
    }
    float mean[4], rstd[4];
#pragma unroll
    for (int r = 0; r < 4; ++r) {
        mean[r] = s[r] * (1.0f / 256.0f);
        float var = sq[r] * (1.0f / 256.0f) - mean[r] * mean[r];
        rstd[r] = rsqrtf(var + 1e-5f);
    }
#pragma unroll
    for (int nt = 0; nt < 16; ++nt) {
        int col = colB + nt * 16 + l15;
        float gc = gam[col], bc2 = bet[col];
#pragma unroll
        for (int r = 0; r < 4; ++r) {
            float v = (acc[nt][r] - mean[r]) * rstd[r] * gc + bc2;
            if (EPI == 1) v = fmaxf(v, 0.0f) + resid[(zRow + r) * 256 + col];  // relu then residual AFTER LN
            long oi = (zRow + r) * (long)ldOut + col;
            outF[oi] = v;
            if (outB) outB[oi] = (bf16)v;
        }
    }
}

// ---------------- sparse gather attention: block=(b,row), wave=head, lane=dim ----------------
__global__ __launch_bounds__(256) void k_attn(const bf16* __restrict__ qg, const bf16* __restrict__ kg,
                                              const bf16* __restrict__ vg, bf16* __restrict__ og,
                                              const int* __restrict__ cnt, const unsigned short* __restrict__ cols)
{
    __shared__ unsigned short sc[64];
    __shared__ float sp[4][64];
    int row = blockIdx.x;
    int b = row >> 11, i = row & 2047;
    int tid = threadIdx.x, h = tid >> 6, lane = tid & 63;
    int c = cnt[i];
    if (tid < 64) sc[tid] = cols[(long)i * 64 + tid];
    __syncthreads();
    long qoff = (long)row * 256 + h * 64 + lane;
    float qd = (float)qg[qoff];
    long kvBase = (long)b * 2048;
    for (int j = 0; j < c; ++j) {
        int col = sc[j];
        float kd = (float)kg[(kvBase + col) * 256 + h * 64 + lane];
        float p = qd * kd;
#pragma unroll
        for (int off = 32; off >= 1; off >>= 1) p += __shfl_xor(p, off);
        if (lane == 0) sp[h][j] = p * 0.125f;  // 1/sqrt(64)
    }
    __syncthreads();
    float sj = (lane < c) ? sp[h][lane] : -3.0e38f;
    float mx = sj;
#pragma unroll
    for (int off = 32; off >= 1; off >>= 1) mx = fmaxf(mx, __shfl_xor(mx, off));
    float e = (lane < c) ? __expf(sj - mx) : 0.0f;
    float ssum = e;
#pragma unroll
    for (int off = 32; off >= 1; off >>= 1) ssum += __shfl_xor(ssum, off);
    if (lane < c) sp[h][lane] = e / ssum;
    __syncthreads();
    float acc = 0.0f;
    for (int j = 0; j < c; ++j) {
        int col = sc[j];
        acc += sp[h][j] * (float)vg[(kvBase + col) * 256 + h * 64 + lane];
    }
    og[qoff] = (bf16)acc;
}

// ---------------- launcher ----------------
extern "C" void kernel_launch(void* const* d_in, const int* in_sizes, int n_in,
                              void* d_out, int out_size, void* d_ws, size_t ws_size,
                              hipStream_t stream)
{
    const float* x   = (const float*)d_in[0];
    const float* L   = (const float*)d_in[1];
    const float* adj = (const float*)d_in[2];
    const float* Wc  = (const float*)d_in[3];
    const float* bc  = (const float*)d_in[4];
    const float* g1  = (const float*)d_in[5];
    const float* be1 = (const float*)d_in[6];
    const float* Wq  = (const float*)d_in[7];
    const float* Wk  = (const float*)d_in[8];
    const float* Wv  = (const float*)d_in[9];
    const float* Wo  = (const float*)d_in[10];
    const float* bo  = (const float*)d_in[11];
    const float* g2  = (const float*)d_in[12];
    const float* be2 = (const float*)d_in[13];
    const float* W1  = (const float*)d_in[14];
    const float* b1  = (const float*)d_in[15];
    const float* W2  = (const float*)d_in[16];
    const float* b2  = (const float*)d_in[17];
    const float* g3  = (const float*)d_in[18];
    const float* be3 = (const float*)d_in[19];
    float* out = (float*)d_out;

    char* ws = (char*)d_ws;
    size_t off = 0;
    auto alloc = [&](size_t bytes) -> void* {
        void* p = ws + off;
        off = (off + bytes + 255) & ~(size_t)255;
        return p;
    };
    float* lam           = (float*)alloc(256);
    int* cnt             = (int*)alloc(2048 * 4);
    unsigned short* cols = (unsigned short*)alloc(2048 * 64 * 2);
    bf16* WcT = (bf16*)alloc(65536 * 2);
    bf16* WqT = (bf16*)alloc(65536 * 2);   // WqT,WkT,WvT contiguous (btZ = 65536)
    bf16* WkT = (bf16*)alloc(65536 * 2);
    bf16* WvT = (bf16*)alloc(65536 * 2);
    bf16* WoT = (bf16*)alloc(65536 * 2);
    bf16* W1T = (bf16*)alloc(131072 * 2);
    bf16* W2T = (bf16*)alloc(131072 * 2);
    bf16* xT  = (bf16*)alloc((size_t)4 * 256 * 2048 * 2);
    bf16* xp  = (bf16*)alloc((size_t)8192 * 256 * 2);
    float* x1f = (float*)alloc((size_t)8192 * 256 * 4);
    bf16* x1b  = (bf16*)alloc((size_t)8192 * 256 * 2);
    bf16* qb   = (bf16*)alloc((size_t)3 * 8192 * 256 * 2);
    bf16* ob   = (bf16*)alloc((size_t)8192 * 256 * 2);
    float* x2f = (float*)alloc((size_t)8192 * 256 * 4);
    bf16* x2b  = (bf16*)alloc((size_t)8192 * 256 * 2);
    bf16* m1   = (bf16*)alloc((size_t)8192 * 512 * 2);
    (void)in_sizes; (void)n_in; (void)out_size; (void)ws_size;

    dim3 blk(256);
    // sparse structure + lam_max
    k_csr<<<dim3(512), blk, 0, stream>>>(adj, cnt, cols);
    k_power<<<dim3(1), dim3(1024), 0, stream>>>(cnt, cols, lam);
    // all transposes (weights + x) in ONE launch; out-of-range blocks exit
    k_trans_all<<<dim3(16, 64, 11), blk, 0, stream>>>(Wc, Wq, Wk, Wv, Wo, W1, W2, x,
                                                      WcT, WqT, WkT, WvT, WoT, W1T, W2T, xT);

    // xp[b] = (2L/lam - I) @ x[b]    (A=L fp32 w/ on-the-fly transform, BT=xT per batch)
    k_gemm<0, 1, 0><<<dim3(32, 1, 4), blk, 0, stream>>>(
        (const void*)L, xT, nullptr, xp, nullptr, nullptr, nullptr, nullptr, lam,
        2048, 2048, 0L, (long)256 * 2048, 2048L, 256);
    // x1 = relu(LN(xp@Wc + bc; g1,be1)) + x
    k_gemm<1, 0, 1><<<dim3(128, 1, 1), blk, 0, stream>>>(
        (const void*)xp, WcT, x1f, x1b, bc, x, g1, be1, nullptr,
        256, 256, 0L, 0L, 0L, 256);
    // q,k,v = x1 @ {Wq,Wk,Wv}
    k_gemm<1, 0, 0><<<dim3(128, 1, 3), blk, 0, stream>>>(
        (const void*)x1b, WqT, nullptr, qb, nullptr, nullptr, nullptr, nullptr, nullptr,
        256, 256, 0L, 65536L, 8192L, 256);
    // sparse masked attention
    bf16* kb  = qb + (size_t)8192 * 256;
    bf16* vb2 = qb + (size_t)2 * 8192 * 256;
    k_attn<<<dim3(8192), blk, 0, stream>>>(qb, kb, vb2, ob, cnt, cols);
    // x2 = LN(x1 + o@Wo + bo; g2,be2)
    k_gemm<1, 0, 2><<<dim3(128, 1, 1), blk, 0, stream>>>(
        (const void*)ob, WoT, x2f, x2b, bo, x1f, g2, be2, nullptr,
        256, 256, 0L, 0L, 0L, 256);
    // m1 = gelu(x2@W1 + b1)
    k_gemm<1, 0, 3><<<dim3(128, 2, 1), blk, 0, stream>>>(
        (const void*)x2b, W1T, nullptr, m1, b1, nullptr, nullptr, nullptr, nullptr,
        256, 256, 0L, 0L, 0L, 512);
    // out = LN(x2 + m1@W2 + b2; g3,be3)
    k_gemm<1, 0, 2><<<dim3(128, 1, 1), blk, 0, stream>>>(
        (const void*)m1, W2T, out, nullptr, b2, x2f, g3, be3, nullptr,
        512, 512, 0L, 0L, 0L, 256);
}

// Round 3
// 411.538 us; speedup vs baseline: 3.6235x; 1.4070x over previous
//
#include <hip/hip_runtime.h>
#include <math.h>

typedef __bf16 bf16;
typedef bf16 bf16x8 __attribute__((ext_vector_type(8)));
typedef float f32x4 __attribute__((ext_vector_type(4)));

#define LDS_PAD 40  // 32 k-elems padded to 40 -> 80B row stride, 2-way-max bank aliasing
#define SENT 2048   // sentinel col index; v[SENT] == 0

// ---------------- k_pre: all transposes (fp32 -> bf16, k-contig) + CSR build, ONE launch ----
__global__ __launch_bounds__(256) void k_pre(
    const float* __restrict__ Wc, const float* __restrict__ Wq, const float* __restrict__ Wk,
    const float* __restrict__ Wv, const float* __restrict__ Wo, const float* __restrict__ W1,
    const float* __restrict__ W2, const float* __restrict__ x, const float* __restrict__ adj,
    bf16* __restrict__ WcT, bf16* __restrict__ WqT, bf16* __restrict__ WkT,
    bf16* __restrict__ WvT, bf16* __restrict__ WoT, bf16* __restrict__ W1T,
    bf16* __restrict__ W2T, bf16* __restrict__ xT,
    int* __restrict__ cnt, unsigned short* __restrict__ cols)
{
    __shared__ float tile[32][33];
    int z = blockIdx.z;
    if (z == 11) {  // ---- CSR of adjacency (incl self loops), <=64/row, sentinel-padded ----
        int flat = blockIdx.y * 16 + blockIdx.x;
        if (flat >= 512) return;
        int row = flat * 4 + (threadIdx.x >> 6);
        int lane = threadIdx.x & 63;
        int base = 0;
        for (int c0 = 0; c0 < 2048; c0 += 64) {
            float a = adj[(long)row * 2048 + c0 + lane];
            unsigned long long m = __ballot(a != 0.0f);
            if (a != 0.0f) {
                int pos = base + __popcll(m & ((1ull << lane) - 1ull));
                if (pos < 64) cols[(long)row * 64 + pos] = (unsigned short)(c0 + lane);
            }
            base += __popcll(m);
        }
        int c = base < 64 ? base : 64;
        if (lane >= c) cols[(long)row * 64 + lane] = (unsigned short)SENT;
        if (lane == 0) cnt[row] = c;
        return;
    }
    const float* src; bf16* dst; int R, C;
    switch (z) {
        case 0: src = Wc; dst = WcT; R = 256; C = 256; break;
        case 1: src = Wq; dst = WqT; R = 256; C = 256; break;
        case 2: src = Wk; dst = WkT; R = 256; C = 256; break;
        case 3: src = Wv; dst = WvT; R = 256; C = 256; break;
        case 4: src = Wo; dst = WoT; R = 256; C = 256; break;
        case 5: src = W1; dst = W1T; R = 256; C = 512; break;
        case 6: src = W2; dst = W2T; R = 512; C = 256; break;
        default: {
            int b = z - 7;
            src = x + (long)b * 2048 * 256; dst = xT + (long)b * 256 * 2048;
            R = 2048; C = 256;
        }
    }
    int c0 = blockIdx.x * 32, r0 = blockIdx.y * 32;
    if (c0 >= C || r0 >= R) return;
    int tx = threadIdx.x & 31, ty = threadIdx.x >> 5;
#pragma unroll
    for (int j = 0; j < 4; ++j)
        tile[ty + 8 * j][tx] = src[(long)(r0 + ty + 8 * j) * C + c0 + tx];
    __syncthreads();
#pragma unroll
    for (int j = 0; j < 4; ++j)
        dst[(long)(c0 + ty + 8 * j) * R + r0 + tx] = (bf16)tile[tx][ty + 8 * j];
}

// ---------------- k_main: block 0 = shifted power iteration; blocks 1..128 = xp0 = L@x ----
// Power: iterate (L - sig*I)v; sig = lamG/6 < lam1/2 (lam1 >= dmax+1). Cols register-hoisted.
// GEMM:  1024 threads, 16 waves; wave w: rows (w&3)*16.., nt tiles (w>>2)*4..+4. L exact in bf16.
__global__ __launch_bounds__(1024) void k_main(
    const int* __restrict__ cnt, const unsigned short* __restrict__ cols, float* __restrict__ lamOut,
    const float* __restrict__ L, const bf16* __restrict__ xT, bf16* __restrict__ xp0)
{
    __shared__ float va[2064], vb[2064];
    __shared__ float redf[16], redf2[16];
    __shared__ int   redi[16];
    __shared__ float bcast;
    __shared__ bf16 As[64 * LDS_PAD];
    __shared__ bf16 Bs[256 * LDS_PAD];

    int t = threadIdx.x;
    if (blockIdx.x != 0) {
        // ================= xp0 GEMM: out[z][m][n] = sum_k L[m][k] * xT[z][n][k] =============
        int bx = blockIdx.x - 1;
        int rowBlk = (bx & 31) * 64;
        int z = bx >> 5;
        const bf16* BT = xT + (long)z * 256 * 2048;
        int w = t >> 6, lane = t & 63;
        int q = lane >> 4, l15 = lane & 15;
        int wm = w & 3, wn = w >> 2;  // wave's row group / nt group

        f32x4 acc[4];
#pragma unroll
        for (int i = 0; i < 4; ++i) acc[i] = (f32x4){0.0f, 0.0f, 0.0f, 0.0f};

        int ar = t >> 4, ac = (t & 15) * 2;   // A: 64x32 fp32, 2 elems/thread
        int br = t >> 2, bc = (t & 3) * 8;    // B: 256x32 bf16, 8 elems/thread
        for (int kt = 0; kt < 2048; kt += 32) {
            {
                const float* p = L + (long)(rowBlk + ar) * 2048 + kt + ac;
                float2 f = *(const float2*)p;
                union { bf16 h[2]; unsigned u; } pk;
                pk.h[0] = (bf16)f.x; pk.h[1] = (bf16)f.y;
                *(unsigned*)&As[ar * LDS_PAD + ac] = pk.u;
            }
            {
                const bf16* p = BT + (long)br * 2048 + kt + bc;
                *(uint4*)&Bs[br * LDS_PAD + bc] = *(const uint4*)p;
            }
            __syncthreads();
            bf16x8 a = *(const bf16x8*)&As[(wm * 16 + l15) * LDS_PAD + q * 8];
#pragma unroll
            for (int nt = 0; nt < 4; ++nt) {
                bf16x8 b = *(const bf16x8*)&Bs[((wn * 4 + nt) * 16 + l15) * LDS_PAD + q * 8];
                acc[nt] = __builtin_amdgcn_mfma_f32_16x16x32_bf16(a, b, acc[nt], 0, 0, 0);
            }
            __syncthreads();
        }
        long zRow = (long)z * 2048 + rowBlk + wm * 16 + q * 4;
#pragma unroll
        for (int nt = 0; nt < 4; ++nt) {
            int col = (wn * 4 + nt) * 16 + l15;
#pragma unroll
            for (int r = 0; r < 4; ++r)
                xp0[(zRow + r) * 256 + col] = (bf16)acc[nt][r];
        }
        return;
    }
    // ================= shifted power iteration (single block, 1024 threads) =================
    int wid = t >> 6, lane = t & 63;
    int r0 = t, r1 = t + 1024;
    int c0 = cnt[r0], c1 = cnt[r1];
    int p0 = (c0 + 7) & ~7, p1 = (c1 + 7) & ~7;

    uint4 cr0[8], cr1[8];  // register-hoisted ELL cols (always in-bounds: rows are 64-wide)
#pragma unroll
    for (int j = 0; j < 8; ++j) {
        cr0[j] = ((const uint4*)(cols + (long)r0 * 64))[j];
        cr1[j] = ((const uint4*)(cols + (long)r1 * 64))[j];
    }

    // lamG = 2*maxdeg (Gershgorin); shift sig = lamG/6 (< lam1/2 since lam1 >= dmax+1)
    int md = max(c0, c1);
#pragma unroll
    for (int off = 32; off >= 1; off >>= 1) md = max(md, __shfl_xor(md, off));
    if (lane == 0) redi[wid] = md;
    __syncthreads();
    if (t == 0) {
        int m = 0;
        for (int i = 0; i < 16; ++i) m = max(m, redi[i]);
        bcast = (float)(2 * (m - 1));
    }
    for (int i = t; i < 2048; i += 1024) {  // pseudo-random +/- init (avoid the 0-eigenvector 1)
        unsigned u = (unsigned)i * 2654435761u;
        u ^= u >> 16; u *= 2246822519u; u ^= u >> 13;
        float mag = 0.5f + (float)((u >> 9) & 1023) * (1.0f / 1024.0f);
        va[i] = (u & 1) ? mag : -mag;
    }
    if (t == 0) { va[SENT] = 0.0f; vb[SENT] = 0.0f; }
    __syncthreads();
    float lamG = bcast;
    float sig = lamG * (1.0f / 6.0f);
    float inv = 1.0f / fmaxf(lamG - sig, 1.0f);
    float ds0 = (float)c0 - sig, ds1 = (float)c1 - sig;

    float* cur = va; float* nxt = vb;
    for (int it = 0; it < 32; ++it) {
        float d0 = cur[r0], d1 = cur[r1];
        float sum0 = 0.0f, sum1 = 0.0f;
#pragma unroll
        for (int j = 0; j < 8; ++j)
            if (j * 8 < p0) {
                uint4 q = cr0[j];
                sum0 += cur[q.x & 0xffff] + cur[q.x >> 16] + cur[q.y & 0xffff] + cur[q.y >> 16]
                      + cur[q.z & 0xffff] + cur[q.z >> 16] + cur[q.w & 0xffff] + cur[q.w >> 16];
            }
#pragma unroll
        for (int j = 0; j < 8; ++j)
            if (j * 8 < p1) {
                uint4 q = cr1[j];
                sum1 += cur[q.x & 0xffff] + cur[q.x >> 16] + cur[q.y & 0xffff] + cur[q.y >> 16]
                      + cur[q.z & 0xffff] + cur[q.z >> 16] + cur[q.w & 0xffff] + cur[q.w >> 16];
            }
        nxt[r0] = (ds0 * d0 - sum0) * inv;
        nxt[r1] = (ds1 * d1 - sum1) * inv;
        __syncthreads();
        float* tmp = cur; cur = nxt; nxt = tmp;
        if ((it & 15) == 15) {  // renorm
            float p = cur[r0] * cur[r0] + cur[r1] * cur[r1];
#pragma unroll
            for (int off = 32; off >= 1; off >>= 1) p += __shfl_xor(p, off);
            if (lane == 0) redf[wid] = p;
            __syncthreads();
            if (t == 0) {
                float s = 0; for (int i = 0; i < 16; ++i) s += redf[i];
                bcast = s;
            }
            __syncthreads();
            float sc = rsqrtf(fmaxf(bcast, 1e-30f));
            cur[r0] *= sc; cur[r1] *= sc;
            __syncthreads();
        }
    }
    // exact fp32 Rayleigh quotient on UNSHIFTED L
    float d0 = cur[r0], d1 = cur[r1];
    float sum0 = 0.0f, sum1 = 0.0f;
#pragma unroll
    for (int j = 0; j < 8; ++j)
        if (j * 8 < p0) {
            uint4 q = cr0[j];
            sum0 += cur[q.x & 0xffff] + cur[q.x >> 16] + cur[q.y & 0xffff] + cur[q.y >> 16]
                  + cur[q.z & 0xffff] + cur[q.z >> 16] + cur[q.w & 0xffff] + cur[q.w >> 16];
        }
#pragma unroll
    for (int j = 0; j < 8; ++j)
        if (j * 8 < p1) {
            uint4 q = cr1[j];
            sum1 += cur[q.x & 0xffff] + cur[q.x >> 16] + cur[q.y & 0xffff] + cur[q.y >> 16]
                  + cur[q.z & 0xffff] + cur[q.z >> 16] + cur[q.w & 0xffff] + cur[q.w >> 16];
        }
    float num = ((float)c0 * d0 - sum0) * d0 + ((float)c1 * d1 - sum1) * d1;
    float den = d0 * d0 + d1 * d1;
#pragma unroll
    for (int off = 32; off >= 1; off >>= 1) { num += __shfl_xor(num, off); den += __shfl_xor(den, off); }
    if (lane == 0) { redf[wid] = num; redf2[wid] = den; }
    __syncthreads();
    if (t == 0) {
        float n = 0, d = 0;
        for (int i = 0; i < 16; ++i) { n += redf[i]; d += redf2[i]; }
        lamOut[0] = (d > 0.0f ? n / d : 0.0f) + 1e-8f;
    }
}

// ---------------- bf16 MFMA GEMM, BM=64 BN=256 BK=32, fused epilogues ----------------
// out[m][n] = sum_k A[m][k] * BT[n][k]
// TA: 1 = A bf16 | 2 = A_eff = (2/lam)*A_bf16 - Aaux_f32  (the L_norm affine, deferred)
// EPI: 0 = store bf16 | 1 = +bias,LN,relu,+resid -> f32+bf16 | 2 = +bias,+resid,LN -> f32(+bf16) | 3 = +bias,gelu -> bf16
template <int TA, int EPI>
__global__ __launch_bounds__(256) void k_gemm(
    const bf16* __restrict__ A0, const float* __restrict__ Aaux, const bf16* __restrict__ BTg,
    float* __restrict__ outF, bf16* __restrict__ outB,
    const float* __restrict__ bias, const float* __restrict__ resid,
    const float* __restrict__ gam, const float* __restrict__ bet,
    const float* __restrict__ lamPtr,
    int K, long aZ, long btZ, long outZrows, int ldOut)
{
    __shared__ bf16 As[64 * LDS_PAD];
    __shared__ bf16 Bs[256 * LDS_PAD];

    int tid = threadIdx.x;
    int w = tid >> 6, lane = tid & 63;
    int q = lane >> 4, l15 = lane & 15;
    int rowBlk = blockIdx.x * 64;
    int colB = blockIdx.y * 256;
    const bf16* BT = BTg + (long)blockIdx.z * btZ + (long)blockIdx.y * 256 * (long)K;

    float s2 = 0.0f;
    if (TA == 2) s2 = 2.0f / lamPtr[0];

    f32x4 acc[16];
#pragma unroll
    for (int i = 0; i < 16; ++i) acc[i] = (f32x4){0.0f, 0.0f, 0.0f, 0.0f};

    int ar = tid >> 2, ac = (tid & 3) * 8;
    for (int kt = 0; kt < K; kt += 32) {
        {   // stage A tile 64x32
            long base = (long)(rowBlk + ar) * K + kt + ac;
            const bf16* A = A0 + (long)blockIdx.z * aZ;
            if (TA == 1) {
                *(uint4*)&As[ar * LDS_PAD + ac] = *(const uint4*)(A + base);
            } else {
                union { bf16 h[8]; uint4 u; } in; in.u = *(const uint4*)(A + base);
                float4 f0 = *(const float4*)(Aaux + base);
                float4 f1 = *(const float4*)(Aaux + base + 4);
                float xa[8] = {f0.x, f0.y, f0.z, f0.w, f1.x, f1.y, f1.z, f1.w};
                union { bf16 h[8]; uint4 u; } pk;
#pragma unroll
                for (int j = 0; j < 8; ++j) pk.h[j] = (bf16)(s2 * (float)in.h[j] - xa[j]);
                *(uint4*)&As[ar * LDS_PAD + ac] = pk.u;
            }
        }
        {   // stage BT tile 256x32
            const bf16* p = BT + (long)tid * K + kt;
            uint4 u0 = ((const uint4*)p)[0];
            uint4 u1 = ((const uint4*)p)[1];
            uint4 u2 = ((const uint4*)p)[2];
            uint4 u3 = ((const uint4*)p)[3];
            bf16* d = &Bs[tid * LDS_PAD];
            *(uint4*)(d + 0)  = u0;
            *(uint4*)(d + 8)  = u1;
            *(uint4*)(d + 16) = u2;
            *(uint4*)(d + 24) = u3;
        }
        __syncthreads();
        bf16x8 a = *(const bf16x8*)&As[(w * 16 + l15) * LDS_PAD + q * 8];
#pragma unroll
        for (int nt = 0; nt < 16; ++nt) {
            bf16x8 b = *(const bf16x8*)&Bs[(nt * 16 + l15) * LDS_PAD + q * 8];
            acc[nt] = __builtin_amdgcn_mfma_f32_16x16x32_bf16(a, b, acc[nt], 0, 0, 0);
        }
        __syncthreads();
    }

    long zRow = (long)blockIdx.z * outZrows + rowBlk + w * 16 + q * 4;  // + r

    if (EPI == 0) {
#pragma unroll
        for (int nt = 0; nt < 16; ++nt) {
            int col = colB + nt * 16 + l15;
#pragma unroll
            for (int r = 0; r < 4; ++r)
                outB[(zRow + r) * (long)ldOut + col] = (bf16)acc[nt][r];
        }
        return;
    }
    if (EPI == 3) {
#pragma unroll
        for (int nt = 0; nt < 16; ++nt) {
            int col = colB + nt * 16 + l15;
            float bi = bias[col];
#pragma unroll
            for (int r = 0; r < 4; ++r) {
                float v = acc[nt][r] + bi;
                float g = 0.5f * v * (1.0f + erff(v * 0.70710678118654752440f));
                outB[(zRow + r) * (long)ldOut + col] = (bf16)g;
            }
        }
        return;
    }
    float s[4] = {0, 0, 0, 0}, sq[4] = {0, 0, 0, 0};
#pragma unroll
    for (int nt = 0; nt < 16; ++nt) {
        int col = colB + nt * 16 + l15;
        float bi = bias[col];
#pragma unroll
        for (int r = 0; r < 4; ++r) {
            float v = acc[nt][r] + bi;
            if (EPI == 2) v += resid[(zRow + r) * 256 + col];
            acc[nt][r] = v;
            s[r] += v; sq[r] += v * v;
        }
    }
#pragma unroll
    for (int off = 1; off <= 8; off <<= 1) {
#pragma unroll
        for (int r = 0; r < 4; ++r) { s[r] += __shfl_xor(s[r], off); sq[r] += __shfl_xor(sq[r], off); }
    }
    float mean[4], rstd[4];
#pragma unroll
    for (int r = 0; r < 4; ++r) {
        mean[r] = s[r] * (1.0f / 256.0f);
        float var = sq[r] * (1.0f / 256.0f) - mean[r] * mean[r];
        rstd[r] = rsqrtf(var + 1e-5f);
    }
#pragma unroll
    for (int nt = 0; nt < 16; ++nt) {
        int col = colB + nt * 16 + l15;
        float gc = gam[col], bc2 = bet[col];
#pragma unroll
        for (int r = 0; r < 4; ++r) {
            float v = (acc[nt][r] - mean[r]) * rstd[r] * gc + bc2;
            if (EPI == 1) v = fmaxf(v, 0.0f) + resid[(zRow + r) * 256 + col];
            long oi = (zRow + r) * (long)ldOut + col;
            outF[oi] = v;
            if (outB) outB[oi] = (bf16)v;
        }
    }
}

// ---------------- sparse gather attention: block=(b,row), wave=head, lane=dim ----------------
__global__ __launch_bounds__(256) void k_attn(const bf16* __restrict__ qg, const bf16* __restrict__ kg,
                                              const bf16* __restrict__ vg, bf16* __restrict__ og,
                                              const int* __restrict__ cnt, const unsigned short* __restrict__ cols)
{
    __shared__ unsigned short sc[64];
    __shared__ float sp[4][64];
    int row = blockIdx.x;
    int b = row >> 11, i = row & 2047;
    int tid = threadIdx.x, h = tid >> 6, lane = tid & 63;
    int c = cnt[i];
    if (tid < 64) sc[tid] = cols[(long)i * 64 + tid];
    __syncthreads();
    long qoff = (long)row * 256 + h * 64 + lane;
    float qd = (float)qg[qoff];
    long kvBase = (long)b * 2048;
    for (int j = 0; j < c; ++j) {
        int col = sc[j];
        float kd = (float)kg[(kvBase + col) * 256 + h * 64 + lane];
        float p = qd * kd;
#pragma unroll
        for (int off = 32; off >= 1; off >>= 1) p += __shfl_xor(p, off);
        if (lane == 0) sp[h][j] = p * 0.125f;
    }
    __syncthreads();
    float sj = (lane < c) ? sp[h][lane] : -3.0e38f;
    float mx = sj;
#pragma unroll
    for (int off = 32; off >= 1; off >>= 1) mx = fmaxf(mx, __shfl_xor(mx, off));
    float e = (lane < c) ? __expf(sj - mx) : 0.0f;
    float ssum = e;
#pragma unroll
    for (int off = 32; off >= 1; off >>= 1) ssum += __shfl_xor(ssum, off);
    if (lane < c) sp[h][lane] = e / ssum;
    __syncthreads();
    float acc = 0.0f;
    for (int j = 0; j < c; ++j) {
        int col = sc[j];
        acc += sp[h][j] * (float)vg[(kvBase + col) * 256 + h * 64 + lane];
    }
    og[qoff] = (bf16)acc;
}

// ---------------- launcher ----------------
extern "C" void kernel_launch(void* const* d_in, const int* in_sizes, int n_in,
                              void* d_out, int out_size, void* d_ws, size_t ws_size,
                              hipStream_t stream)
{
    const float* x   = (const float*)d_in[0];
    const float* L   = (const float*)d_in[1];
    const float* adj = (const float*)d_in[2];
    const float* Wc  = (const float*)d_in[3];
    const float* bc  = (const float*)d_in[4];
    const float* g1  = (const float*)d_in[5];
    const float* be1 = (const float*)d_in[6];
    const float* Wq  = (const float*)d_in[7];
    const float* Wk  = (const float*)d_in[8];
    const float* Wv  = (const float*)d_in[9];
    const float* Wo  = (const float*)d_in[10];
    const float* bo  = (const float*)d_in[11];
    const float* g2  = (const float*)d_in[12];
    const float* be2 = (const float*)d_in[13];
    const float* W1  = (const float*)d_in[14];
    const float* b1  = (const float*)d_in[15];
    const float* W2  = (const float*)d_in[16];
    const float* b2  = (const float*)d_in[17];
    const float* g3  = (const float*)d_in[18];
    const float* be3 = (const float*)d_in[19];
    float* out = (float*)d_out;

    char* ws = (char*)d_ws;
    size_t off = 0;
    auto alloc = [&](size_t bytes) -> void* {
        void* p = ws + off;
        off = (off + bytes + 255) & ~(size_t)255;
        return p;
    };
    float* lam           = (float*)alloc(256);
    int* cnt             = (int*)alloc(2048 * 4);
    unsigned short* cols = (unsigned short*)alloc(2048 * 64 * 2);
    bf16* WcT = (bf16*)alloc(65536 * 2);
    bf16* WqT = (bf16*)alloc(65536 * 2);   // WqT,WkT,WvT contiguous (btZ = 65536)
    bf16* WkT = (bf16*)alloc(65536 * 2);
    bf16* WvT = (bf16*)alloc(65536 * 2);
    bf16* WoT = (bf16*)alloc(65536 * 2);
    bf16* W1T = (bf16*)alloc(131072 * 2);
    bf16* W2T = (bf16*)alloc(131072 * 2);
    bf16* xT  = (bf16*)alloc((size_t)4 * 256 * 2048 * 2);
    bf16* xp0 = (bf16*)alloc((size_t)8192 * 256 * 2);
    float* x1f = (float*)alloc((size_t)8192 * 256 * 4);
    bf16* x1b  = (bf16*)alloc((size_t)8192 * 256 * 2);
    bf16* qb   = (bf16*)alloc((size_t)3 * 8192 * 256 * 2);
    bf16* ob   = (bf16*)alloc((size_t)8192 * 256 * 2);
    float* x2f = (float*)alloc((size_t)8192 * 256 * 4);
    bf16* x2b  = (bf16*)alloc((size_t)8192 * 256 * 2);
    bf16* m1   = (bf16*)alloc((size_t)8192 * 512 * 2);
    (void)in_sizes; (void)n_in; (void)out_size; (void)ws_size;

    dim3 blk(256);
    // transposes + CSR, one launch
    k_pre<<<dim3(16, 64, 12), blk, 0, stream>>>(Wc, Wq, Wk, Wv, Wo, W1, W2, x, adj,
                                                WcT, WqT, WkT, WvT, WoT, W1T, W2T, xT, cnt, cols);
    // block 0: shifted power iteration -> lam ; blocks 1..128: xp0[b] = L @ x[b] (lam-free)
    k_main<<<dim3(129), dim3(1024), 0, stream>>>(cnt, cols, lam, L, xT, xp0);
    // x1 = relu(LN((s2*xp0 - x)@Wc + bc; g1,be1)) + x   (L_norm affine folded into A-staging)
    k_gemm<2, 1><<<dim3(128, 1, 1), blk, 0, stream>>>(
        xp0, x, WcT, x1f, x1b, bc, x, g1, be1, lam,
        256, 0L, 0L, 0L, 256);
    // q,k,v = x1 @ {Wq,Wk,Wv}
    k_gemm<1, 0><<<dim3(128, 1, 3), blk, 0, stream>>>(
        x1b, nullptr, WqT, nullptr, qb, nullptr, nullptr, nullptr, nullptr, nullptr,
        256, 0L, 65536L, 8192L, 256);
    // sparse masked attention
    bf16* kb  = qb + (size_t)8192 * 256;
    bf16* vb2 = qb + (size_t)2 * 8192 * 256;
    k_attn<<<dim3(8192), blk, 0, stream>>>(qb, kb, vb2, ob, cnt, cols);
    // x2 = LN(x1 + o@Wo + bo; g2,be2)
    k_gemm<1, 2><<<dim3(128, 1, 1), blk, 0, stream>>>(
        ob, nullptr, WoT, x2f, x2b, bo, x1f, g2, be2, nullptr,
        256, 0L, 0L, 0L, 256);
    // m1 = gelu(x2@W1 + b1)
    k_gemm<1, 3><<<dim3(128, 2, 1), blk, 0, stream>>>(
        x2b, nullptr, W1T, nullptr, m1, b1, nullptr, nullptr, nullptr, nullptr,
        256, 0L, 0L, 0L, 512);
    // out = LN(x2 + m1@W2 + b2; g3,be3)
    k_gemm<1, 2><<<dim3(128, 1, 1), blk, 0, stream>>>(
        m1, nullptr, W2T, out, nullptr, b2, x2f, g3, be3, nullptr,
        512, 0L, 0L, 0L, 256);
}